// Round 8
// baseline (109141.882 us; speedup 1.0000x reference)
//
#include <hip/hip_runtime.h>
#include <math.h>

// ODE-RNN, T=8192, IN=512, H=1024, OUT=256, 4 euler substeps/step.
// R8: critical-path strip-down of the 6-handoff/step dataflow (R4 shape).
//   z = W_f1 h + b_f1, M = W_f1 W_f2, P = W_h W_f2 (precomputed GEMMs)
//   4x substep: publish u=tanh(z); z += dt(M u + c1)      [M-dot only]
//   y4 = W_h h + dt*P*(u1+u2+u3+u4) + 4 dt c2             [ONE P-dot/step]
//   a = tanh(y4 + W_in x + b); h' = tanh(W_h2 a + b_h2); z reset from h'.
// Latency levers this round:
//   - W_h2, W_f1 in LDS (ds_read = lgkmcnt: polls never queue behind them);
//     M, P, W_h, W_in in VGPRs. Only per-step vector load = 8 x-loads,
//     issued in phase-6's publish->poll gap (overlap store visibility).
//   - 2-deep pipelined poll: two rotating 4-slot batches in flight ->
//     sampling period ~RT/2 (vmcnt(4) waits, other batch stays out).
//   - usum in LDS: y-path linear in sum(u) -> P-dot once per step.
//   - 3 rotating stage buffers: one barrier per phase; deferred dots
//     (yd at ph2 gap, winx at ph4 gap) read older buffers race-free.
// Handoff: epoch-tagged 8B agent atomics (tag<<32|f32). WAR-safe: full-read
// ring (queue reuse distance >= 2 complete broadcast consumptions).

#define TSTEPS 8192
#define INP    512
#define HDIM   1024
#define NWG    64
#define BLK    256

typedef unsigned long long u64;
typedef unsigned int u32;

__device__ __forceinline__ u64 aload(u64* p) {
    return __hip_atomic_load(p, __ATOMIC_RELAXED, __HIP_MEMORY_SCOPE_AGENT);
}
__device__ __forceinline__ void astore(u64* p, u64 v) {
    __hip_atomic_store(p, v, __ATOMIC_RELAXED, __HIP_MEMORY_SCOPE_AGENT);
}
__device__ __forceinline__ u64 pack(u32 tag, float f) {
    return ((u64)tag << 32) | (u64)__float_as_uint(f);
}

// ---------------- precompute: C = A @ B, 1024x1024x1024 fp32 ----------------
__global__ __launch_bounds__(256)
void mm1024(const float* __restrict__ A, const float* __restrict__ B,
            float* __restrict__ C) {
    __shared__ float As[64][17];
    __shared__ float Bs[16][65];
    const int tid = threadIdx.x;
    const int tx = tid & 15, ty = tid >> 4;
    const int r0 = blockIdx.y * 64, c0 = blockIdx.x * 64;
    float acc[4][4] = {};
    for (int k0 = 0; k0 < HDIM; k0 += 16) {
        const int ar = tid >> 2, ac = (tid & 3) * 4;
        const float4 av = *reinterpret_cast<const float4*>(
            A + (size_t)(r0 + ar) * HDIM + k0 + ac);
        As[ar][ac] = av.x; As[ar][ac + 1] = av.y;
        As[ar][ac + 2] = av.z; As[ar][ac + 3] = av.w;
        const int br = tid >> 4, bc = (tid & 15) * 4;
        const float4 bv = *reinterpret_cast<const float4*>(
            B + (size_t)(k0 + br) * HDIM + c0 + bc);
        Bs[br][bc] = bv.x; Bs[br][bc + 1] = bv.y;
        Bs[br][bc + 2] = bv.z; Bs[br][bc + 3] = bv.w;
        __syncthreads();
        #pragma unroll
        for (int kk = 0; kk < 16; ++kk) {
            float a[4], b[4];
            #pragma unroll
            for (int i2 = 0; i2 < 4; ++i2) a[i2] = As[ty * 4 + i2][kk];
            #pragma unroll
            for (int j2 = 0; j2 < 4; ++j2) b[j2] = Bs[kk][tx * 4 + j2];
            #pragma unroll
            for (int i2 = 0; i2 < 4; ++i2)
                #pragma unroll
                for (int j2 = 0; j2 < 4; ++j2)
                    acc[i2][j2] = fmaf(a[i2], b[j2], acc[i2][j2]);
        }
        __syncthreads();
    }
    #pragma unroll
    for (int i2 = 0; i2 < 4; ++i2)
        #pragma unroll
        for (int j2 = 0; j2 < 4; ++j2)
            C[(size_t)(r0 + ty * 4 + i2) * HDIM + c0 + tx * 4 + j2] = acc[i2][j2];
}

// ---------------------------- persistent kernel -----------------------------
__global__ __launch_bounds__(BLK, 1)
void ode_rnn_persistent(
    const float* __restrict__ t,    const float* __restrict__ x,
    const float* __restrict__ W_in, const float* __restrict__ b_in,
    const float* __restrict__ W_h,  const float* __restrict__ b_h,
    const float* __restrict__ W_h2, const float* __restrict__ b_h2,
    const float* __restrict__ W_f1, const float* __restrict__ b_f1,
    const float* __restrict__ b_f2,
    const float* __restrict__ W_dec, const float* __restrict__ b_dec,
    const float* __restrict__ Mw,   const float* __restrict__ Pw,
    float* __restrict__ out,
    u64* QA, u64* QB, u64* QC, u64* QD)
{
    extern __shared__ float smem[];
    float* wh2l = smem;                 // [16][1024] own W_h2 rows
    float* wf1l = smem + 16 * 1024;     // [16][1024] own W_f1 rows
    float* sb0  = smem + 32 * 1024;     // 3 rotating stage buffers
    float* sb1  = sb0 + 1024;
    float* sb2  = sb1 + 1024;
    float* us   = sb2 + 1024;           // usum accumulator

    const int tid  = threadIdx.x;
    const int wg   = blockIdx.x;
    const int seg  = tid & 15;                 // 16 lanes per row
    const int rloc = tid >> 4;                 // local row 0..15
    const int row  = wg * 16 + rloc;           // owned global row

    // ---- LDS weight preload (own 16 rows of W_h2, W_f1) ----
    {
        const float* s2 = W_h2 + (size_t)wg * 16 * HDIM;
        const float* s1 = W_f1 + (size_t)wg * 16 * HDIM;
        for (int k = 0; k < 16; ++k) {
            const int idx = k * 1024 + tid * 4;
            *reinterpret_cast<float4*>(wh2l + idx) =
                *reinterpret_cast<const float4*>(s2 + idx);
            *reinterpret_cast<float4*>(wf1l + idx) =
                *reinterpret_cast<const float4*>(s1 + idx);
        }
    }

    // ---- permanent register weights ----
    float4 m16[16], p16[16], whr[16], wir[8], xr[8];
    {
        const float4* pM = reinterpret_cast<const float4*>(Mw  + (size_t)row * HDIM);
        const float4* pP = reinterpret_cast<const float4*>(Pw  + (size_t)row * HDIM);
        const float4* pH = reinterpret_cast<const float4*>(W_h + (size_t)row * HDIM);
        #pragma unroll
        for (int j = 0; j < 16; ++j) {
            m16[j] = pM[j * 16 + seg];
            p16[j] = pP[j * 16 + seg];
            whr[j] = pH[j * 16 + seg];
        }
        const float4* pI = reinterpret_cast<const float4*>(W_in + (size_t)row * INP);
        #pragma unroll
        for (int j = 0; j < 8; ++j) wir[j] = pI[j * 16 + seg];
        const float4* xp = reinterpret_cast<const float4*>(x + (size_t)1 * INP);
        #pragma unroll
        for (int j = 0; j < 8; ++j) xr[j] = xp[j * 16 + seg];   // x[1] for step 1
    }

    const float bf1_r = b_f1[row];
    const float bih_r = b_in[row] + b_h[row];
    const float bh2_r = b_h2[row];

    auto red16 = [&](float a) {        // butterfly: all 16 lanes get the sum
        #pragma unroll
        for (int off = 8; off; off >>= 1) a += __shfl_xor(a, off, 16);
        return a;
    };
    auto dotReg = [&](const float4* w, const float* v) {
        float a = 0.f;
        #pragma unroll
        for (int j = 0; j < 16; ++j) {
            const float4 vv = *reinterpret_cast<const float4*>(v + j * 64 + seg * 4);
            a = fmaf(w[j].x, vv.x, a); a = fmaf(w[j].y, vv.y, a);
            a = fmaf(w[j].z, vv.z, a); a = fmaf(w[j].w, vv.w, a);
        }
        return red16(a);
    };
    auto dotW = [&](const float* Wl, const float* v) {   // LDS weights
        const float* wr = Wl + rloc * 1024;
        float a = 0.f;
        #pragma unroll
        for (int j = 0; j < 16; ++j) {
            const float4 w  = *reinterpret_cast<const float4*>(wr + j * 64 + seg * 4);
            const float4 vv = *reinterpret_cast<const float4*>(v  + j * 64 + seg * 4);
            a = fmaf(w.x, vv.x, a); a = fmaf(w.y, vv.y, a);
            a = fmaf(w.z, vv.z, a); a = fmaf(w.w, vv.w, a);
        }
        return red16(a);
    };
    auto pub = [&](u64* q, u32 e, float pre) {
        if (seg == 0) astore(&q[row], pack(e, tanhf(pre)));
    };

    int pb = 0;
    // Pipelined poll (2 batches in flight) + stage into rotating buffer.
    // mode 0: plain; 1: usum = val; 2: usum += val.
    auto stage = [&](u64* q, u32 tag, int mode) -> float* {
        float* dst = (pb == 0) ? sb0 : (pb == 1) ? sb1 : sb2;
        pb = (pb == 2) ? 0 : pb + 1;
        const int i0 = tid, i1 = tid + 256, i2 = tid + 512, i3 = tid + 768;
        u64 A0 = aload(q + i0), A1 = aload(q + i1), A2 = aload(q + i2), A3 = aload(q + i3);
        u64 B0 = aload(q + i0), B1 = aload(q + i1), B2 = aload(q + i2), B3 = aload(q + i3);
        u64 r0, r1, r2, r3;
        for (;;) {
            bool ok = ((u32)(A0 >> 32) == tag) & ((u32)(A1 >> 32) == tag) &
                      ((u32)(A2 >> 32) == tag) & ((u32)(A3 >> 32) == tag);
            if (__all(ok)) { r0 = A0; r1 = A1; r2 = A2; r3 = A3; break; }
            A0 = aload(q + i0); A1 = aload(q + i1); A2 = aload(q + i2); A3 = aload(q + i3);
            ok = ((u32)(B0 >> 32) == tag) & ((u32)(B1 >> 32) == tag) &
                 ((u32)(B2 >> 32) == tag) & ((u32)(B3 >> 32) == tag);
            if (__all(ok)) { r0 = B0; r1 = B1; r2 = B2; r3 = B3; break; }
            B0 = aload(q + i0); B1 = aload(q + i1); B2 = aload(q + i2); B3 = aload(q + i3);
        }
        const float v0 = __uint_as_float((u32)r0), v1 = __uint_as_float((u32)r1);
        const float v2 = __uint_as_float((u32)r2), v3 = __uint_as_float((u32)r3);
        dst[i0] = v0; dst[i1] = v1; dst[i2] = v2; dst[i3] = v3;
        if (mode == 1)      { us[i0]  = v0; us[i1]  = v1; us[i2]  = v2; us[i3]  = v3; }
        else if (mode == 2) { us[i0] += v0; us[i1] += v1; us[i2] += v2; us[i3] += v3; }
        __syncthreads();
        return dst;
    };

    // ---- init: c1 = (W_f1 b_f2)[row], c2 = (W_h b_f2)[row] ----
    __syncthreads();                    // LDS weights ready
    #pragma unroll
    for (int k = 0; k < 4; ++k) sb0[tid + k * 256] = b_f2[tid + k * 256];
    __syncthreads();
    const float c1_own = dotW(wf1l, sb0);
    const float c2_own = dotReg(whr, sb0);
    __syncthreads();                    // protect sb0 before first stage

    float z_own = bf1_r;                // z1 = W_f1*0 + b_f1
    float yd_own = 0.f;                 // W_h h_0 = 0
    u32 eA = 0, eB = 0, eC = 0, eD = 0;
    float* hprev = sb0;

    #pragma unroll 1
    for (int i = 1; i < TSTEPS; ++i) {
        const float dt = (t[i] - t[i - 1]) * 0.25f;

        // ---- phase 1 (u1 -> QA): z += dt(M u1 + c1)
        ++eA;
        pub(QA, eA, z_own);
        float* b1 = stage(QA, eA, 1);
        z_own = fmaf(dt, dotReg(m16, b1) + c1_own, z_own);

        // ---- phase 2 (u2 -> QB); gap: yd = W_h h_{i-1} (reads 2-phase-old buf)
        ++eB;
        pub(QB, eB, z_own);
        if (i > 1) yd_own = dotReg(whr, hprev);
        float* b2 = stage(QB, eB, 2);
        z_own = fmaf(dt, dotReg(m16, b2) + c1_own, z_own);

        // ---- phase 3 (u3 -> QA)
        ++eA;
        pub(QA, eA, z_own);
        float* b3 = stage(QA, eA, 2);
        z_own = fmaf(dt, dotReg(m16, b3) + c1_own, z_own);

        // ---- phase 4 (u4 -> QB); gap: winx (pure VALU); then ONE P-dot on usum
        ++eB;
        pub(QB, eB, z_own);
        float winx;
        {
            float a = 0.f;
            #pragma unroll
            for (int j = 0; j < 8; ++j) {
                a = fmaf(wir[j].x, xr[j].x, a); a = fmaf(wir[j].y, xr[j].y, a);
                a = fmaf(wir[j].z, xr[j].z, a); a = fmaf(wir[j].w, xr[j].w, a);
            }
            winx = red16(a);
        }
        stage(QB, eB, 2);
        const float pd = dotReg(p16, us);
        const float apre = fmaf(dt, pd + 4.f * c2_own, yd_own) + winx + bih_r;

        // ---- phase 5 (a -> QC): h' = tanh(W_h2 a + b_h2), W_h2 from LDS
        ++eC;
        pub(QC, eC, apre);
        float* b5 = stage(QC, eC, 0);
        const float hpre = dotW(wh2l, b5) + bh2_r;

        // ---- phase 6 (h' -> QD); gap: prefetch x for next step (only vector
        //      loads of the whole step — overlap store visibility)
        ++eD;
        pub(QD, eD, hpre);
        {
            const int inext = (i + 1 < TSTEPS) ? i + 1 : i;
            const float4* xp = reinterpret_cast<const float4*>(x + (size_t)inext * INP);
            #pragma unroll
            for (int j = 0; j < 8; ++j) xr[j] = xp[j * 16 + seg];
        }
        float* b6 = stage(QD, eD, 0);
        hprev = b6;
        z_own = dotW(wf1l, b6) + bf1_r;     // z1' for next step, W_f1 from LDS
    }

    // ---- decoder: out = W_dec @ h_T + b_dec (4 rows/WG); h_T in hprev ----
    {
        const int rl = tid >> 6, s2 = tid & 63;
        const int orow = wg * 4 + rl;
        const float4* wd = reinterpret_cast<const float4*>(W_dec + (size_t)orow * HDIM);
        float acc = 0.f;
        #pragma unroll
        for (int j = 0; j < 4; ++j) {
            const float4 w = wd[j * 64 + s2];
            const float4 v = *reinterpret_cast<const float4*>(hprev + j * 256 + s2 * 4);
            acc = fmaf(w.x, v.x, acc); acc = fmaf(w.y, v.y, acc);
            acc = fmaf(w.z, v.z, acc); acc = fmaf(w.w, v.w, acc);
        }
        #pragma unroll
        for (int off = 32; off; off >>= 1) acc += __shfl_down(acc, off, 64);
        if (s2 == 0) out[orow] = acc + b_dec[orow];
    }
}

extern "C" void kernel_launch(void* const* d_in, const int* in_sizes, int n_in,
                              void* d_out, int out_size, void* d_ws, size_t ws_size,
                              hipStream_t stream) {
    const float* t     = (const float*)d_in[0];
    const float* x     = (const float*)d_in[1];
    const float* W_in  = (const float*)d_in[2];
    const float* b_in  = (const float*)d_in[3];
    const float* W_h   = (const float*)d_in[4];
    const float* b_h   = (const float*)d_in[5];
    const float* W_h2  = (const float*)d_in[6];
    const float* b_h2  = (const float*)d_in[7];
    const float* W_f1  = (const float*)d_in[8];
    const float* b_f1  = (const float*)d_in[9];
    const float* W_f2  = (const float*)d_in[10];
    const float* b_f2  = (const float*)d_in[11];
    const float* W_dec = (const float*)d_in[12];
    const float* b_dec = (const float*)d_in[13];
    float* out = (float*)d_out;

    // ws layout: M (4MB) | P (4MB) | QA,QB,QC,QD (4 x 8KB)
    unsigned char* ws = (unsigned char*)d_ws;
    float* Mw = (float*)(ws);
    float* Pw = (float*)(ws + (size_t)4 * 1024 * 1024);
    u64*   QA = (u64*)(ws + (size_t)8 * 1024 * 1024);
    u64*   QB = QA + HDIM;
    u64*   QC = QB + HDIM;
    u64*   QD = QC + HDIM;

    // precompute M = W_f1 @ W_f2, P = W_h @ W_f2 (every call; deterministic)
    mm1024<<<dim3(16, 16), 256, 0, stream>>>(W_f1, W_f2, Mw);
    mm1024<<<dim3(16, 16), 256, 0, stream>>>(W_h,  W_f2, Pw);

    // reset epoch tags to 0 (first expected tag is 1); every call
    hipMemsetAsync(ws + (size_t)8 * 1024 * 1024, 0, 4 * HDIM * sizeof(u64), stream);

    // dynamic LDS: 2 weight panels (128KB) + 3 stage bufs + usum = 144KB
    const size_t smem_bytes = (size_t)(32 * 1024 + 4 * 1024) * sizeof(float);
    ode_rnn_persistent<<<dim3(NWG), dim3(BLK), smem_bytes, stream>>>(
        t, x, W_in, b_in, W_h, b_h, W_h2, b_h2, W_f1, b_f1, b_f2,
        W_dec, b_dec, Mw, Pw, out, QA, QB, QC, QD);
}